// Round 2
// baseline (2007.151 us; speedup 1.0000x reference)
//
#include <hip/hip_runtime.h>

typedef __bf16 bf16_t;
typedef __bf16 bf16x8 __attribute__((ext_vector_type(8)));
typedef float f32x4 __attribute__((ext_vector_type(4)));

#define MFMA_BF16(a, b, c) __builtin_amdgcn_mfma_f32_16x16x32_bf16((a), (b), (c), 0, 0, 0)

static constexpr int Bn = 4096;
static constexpr int Dn = 1024;
static constexpr int Rn = 256;
static constexpr int BT = 32;          // rows per block (two MFMA M-tiles)
static constexpr int V_STRIDE = 1040;  // bf16 elems; 2080 B rows, 16B aligned
static constexpr int T_STRIDE = 264;
static constexpr float DTv = 0.01f;
static constexpr float HDT = 0.005f;

// ---- Pack U [D=1024, R=256] fp32 -> bf16 B-operand fragment layout ----
// Upk[((ct*32 + kb)*64 + lane)*8 + j] = U[kb*32 + (lane>>4)*8 + j][ct*16 + (lane&15)]
__global__ void pack_u_kernel(const float* __restrict__ U, bf16_t* __restrict__ Upk) {
  int t = blockIdx.x * blockDim.x + threadIdx.x;  // 16*32*64 = 32768 threads
  int l = t & 63;
  int f = t >> 6;
  int kb = f & 31;
  int ct = f >> 5;
  int row0 = kb * 32 + (l >> 4) * 8;
  int col = ct * 16 + (l & 15);
  bf16x8 v;
#pragma unroll
  for (int j = 0; j < 8; ++j) v[j] = (bf16_t)U[(size_t)(row0 + j) * Rn + col];
  ((bf16x8*)Upk)[t] = v;
}

// ---- Pack W [R=256, D=1024] fp32 -> bf16 B-operand fragment layout ----
// Wpk[((ct*8 + kb)*64 + lane)*8 + j] = W[kb*32 + (lane>>4)*8 + j][ct*16 + (lane&15)]
__global__ void pack_w_kernel(const float* __restrict__ W, bf16_t* __restrict__ Wpk) {
  int t = blockIdx.x * blockDim.x + threadIdx.x;  // 64*8*64 = 32768 threads
  int l = t & 63;
  int f = t >> 6;
  int kb = f & 7;
  int ct = f >> 3;
  int row0 = kb * 32 + (l >> 4) * 8;
  int col = ct * 16 + (l & 15);
  bf16x8 v;
#pragma unroll
  for (int j = 0; j < 8; ++j) v[j] = (bf16_t)W[(size_t)(row0 + j) * Dn + col];
  ((bf16x8*)Wpk)[t] = v;
}

// ---- Fused integrator: one block owns 32 rows for all steps; hx = x@U cached ----
__global__ __launch_bounds__(1024, 4)
void integrate_kernel(const float* __restrict__ x_in, const float* __restrict__ v_in,
                      const float* __restrict__ force,
                      const bf16_t* __restrict__ Upk, const bf16_t* __restrict__ Wpk,
                      const int* __restrict__ steps_p, float* __restrict__ out) {
  extern __shared__ __align__(16) char lds[];
  bf16_t* vbf = (bf16_t*)lds;            // [32][1040]; holds x-tile during phase 0
  bf16_t* tbf = vbf + BT * V_STRIDE;     // [32][264]

  const int tid = (int)threadIdx.x;
  const int wv = tid >> 6;   // wave 0..15
  const int mt = wv & 1;     // M-tile (rows mt*16..mt*16+16)
  const int wg = wv >> 1;    // column group 0..7
  const int l = tid & 63;
  const int ln = l & 15;
  const int quad = l >> 4;
  const int nhalf = 2 * steps_p[0];
  const int row_base = (int)blockIdx.x * BT + mt * 16;

  float* out_x = out;
  float* out_v = out + (size_t)Bn * Dn;

  // v state in registers, C/D layout: vs[j][r] <-> row row_base+quad*4+r, col (wg*8+j)*16+ln
  float vs[8][4];
  // hx = x@U state for ct = 2wg (hx0) and 2wg+1 (hx1), C/D layout rows of this mt
  f32x4 hx0 = {0.f, 0.f, 0.f, 0.f}, hx1 = {0.f, 0.f, 0.f, 0.f};

  // ---- init: out_x = x; x-tile -> vbf region; v -> regs ----
#pragma unroll
  for (int j = 0; j < 8; ++j) {
    const int col = (wg * 8 + j) * 16 + ln;
#pragma unroll
    for (int r = 0; r < 4; ++r) {
      const size_t g = (size_t)(row_base + quad * 4 + r) * Dn + col;
      const float xv = x_in[g];
      out_x[g] = xv;
      vbf[(mt * 16 + quad * 4 + r) * V_STRIDE + col] = (bf16_t)xv;
      vs[j][r] = v_in[g];
    }
  }
  __syncthreads();

  // ---- gemm over U: acc(ct=2wg, 2wg+1) += tile(vbf) @ U ; 2 streams, depth-4 prefetch ----
  auto gemm_u = [&](f32x4& a0, f32x4& a1) {
    const bf16x8* up = (const bf16x8*)Upk;
    const int ct0 = 2 * wg;
    const bf16_t* arow = vbf + (mt * 16 + ln) * V_STRIDE + quad * 8;
    bf16x8 r0[4], r1[4];
#pragma unroll
    for (int p = 0; p < 4; ++p) {
      r0[p] = up[(ct0 * 32 + p) * 64 + l];
      r1[p] = up[((ct0 + 1) * 32 + p) * 64 + l];
    }
#pragma unroll
    for (int kb = 0; kb < 32; ++kb) {
      const bf16x8 av = *(const bf16x8*)(arow + kb * 32);
      const bf16x8 b0 = r0[kb & 3];
      const bf16x8 b1 = r1[kb & 3];
      if (kb < 28) {
        r0[kb & 3] = up[(ct0 * 32 + kb + 4) * 64 + l];
        r1[kb & 3] = up[((ct0 + 1) * 32 + kb + 4) * 64 + l];
      }
      a0 = MFMA_BF16(av, b0, a0);
      a1 = MFMA_BF16(av, b1, a1);
    }
  };

  // ---- phase 0: hx = x0 @ U ----
  gemm_u(hx0, hx1);
  __syncthreads();  // done reading x tile
#pragma unroll
  for (int j = 0; j < 8; ++j) {
    const int col = (wg * 8 + j) * 16 + ln;
#pragma unroll
    for (int r = 0; r < 4; ++r)
      vbf[(mt * 16 + quad * 4 + r) * V_STRIDE + col] = (bf16_t)vs[j][r];
  }
  __syncthreads();

  for (int h = 0; h < nhalf; ++h) {
    // ---- phase 1: hv = v @ U (ct pair 2wg, 2wg+1) ----
    f32x4 hv0 = {0.f, 0.f, 0.f, 0.f}, hv1 = {0.f, 0.f, 0.f, 0.f};
    gemm_u(hv0, hv1);

    const bool odd = (h & 1) != 0;
    if (odd) {  // x was updated with exactly this velocity: hx += dt * hv
#pragma unroll
      for (int r = 0; r < 4; ++r) { hx0[r] += DTv * hv0[r]; hx1[r] += DTv * hv1[r]; }
    }
    // T = tanh(hx) * hv^2 -> tbf (bf16)
#pragma unroll
    for (int i = 0; i < 2; ++i) {
      const f32x4 hx = i ? hx1 : hx0;
      const f32x4 hv = i ? hv1 : hv0;
      const int col = (2 * wg + i) * 16 + ln;
#pragma unroll
      for (int r = 0; r < 4; ++r) {
        float a = fminf(fmaxf(hx[r], -15.f), 15.f);
        const float e = __expf(2.f * a);
        const float gate = (e - 1.f) / (e + 1.f);
        tbf[(mt * 16 + quad * 4 + r) * T_STRIDE + col] = (bf16_t)(gate * hv[r] * hv[r]);
      }
    }
    __syncthreads();

    // ---- phase 2: gamma = T @ W for D-cts wg*8..wg*8+8 (2 passes x 4 ct, depth-2) ----
#pragma unroll
    for (int pass = 0; pass < 2; ++pass) {
      f32x4 acc[4];
#pragma unroll
      for (int i = 0; i < 4; ++i) acc[i] = (f32x4){0.f, 0.f, 0.f, 0.f};
      const bf16x8* wp = (const bf16x8*)Wpk;
      const int ct0 = wg * 8 + pass * 4;
      const bf16_t* trow = tbf + (mt * 16 + ln) * T_STRIDE + quad * 8;
      bf16x8 rw[4][2];
#pragma unroll
      for (int i = 0; i < 4; ++i) {
        rw[i][0] = wp[((ct0 + i) * 8 + 0) * 64 + l];
        rw[i][1] = wp[((ct0 + i) * 8 + 1) * 64 + l];
      }
#pragma unroll
      for (int kb = 0; kb < 8; ++kb) {
        const bf16x8 at = *(const bf16x8*)(trow + kb * 32);
#pragma unroll
        for (int i = 0; i < 4; ++i) {
          const bf16x8 b = rw[i][kb & 1];
          if (kb < 6) rw[i][kb & 1] = wp[((ct0 + i) * 8 + kb + 2) * 64 + l];
          acc[i] = MFMA_BF16(at, b, acc[i]);
        }
      }
      // fused update: v += hdt*(force - gamma); on even h: x += dt*v (global RMW)
#pragma unroll
      for (int i = 0; i < 4; ++i) {
        const int j = pass * 4 + i;
        const int col = (wg * 8 + j) * 16 + ln;
#pragma unroll
        for (int r = 0; r < 4; ++r) {
          const size_t g = (size_t)(row_base + quad * 4 + r) * Dn + col;
          const float a = force[g] - acc[i][r];
          vs[j][r] += HDT * a;
          if (!odd) out_x[g] += DTv * vs[j][r];
        }
      }
    }
    // refresh v tile for next half-step's phase 1
#pragma unroll
    for (int j = 0; j < 8; ++j) {
      const int col = (wg * 8 + j) * 16 + ln;
#pragma unroll
      for (int r = 0; r < 4; ++r)
        vbf[(mt * 16 + quad * 4 + r) * V_STRIDE + col] = (bf16_t)vs[j][r];
    }
    __syncthreads();
  }

  // ---- store v ----
#pragma unroll
  for (int j = 0; j < 8; ++j) {
    const int col = (wg * 8 + j) * 16 + ln;
#pragma unroll
    for (int r = 0; r < 4; ++r)
      out_v[(size_t)(row_base + quad * 4 + r) * Dn + col] = vs[j][r];
  }
}

extern "C" void kernel_launch(void* const* d_in, const int* in_sizes, int n_in,
                              void* d_out, int out_size, void* d_ws, size_t ws_size,
                              hipStream_t stream) {
  const float* x = (const float*)d_in[0];
  const float* v = (const float*)d_in[1];
  const float* force = (const float*)d_in[2];
  const float* U = (const float*)d_in[3];
  const float* W = (const float*)d_in[4];
  const int* steps = (const int*)d_in[5];

  bf16_t* Upk = (bf16_t*)d_ws;                                  // 512 KB
  bf16_t* Wpk = (bf16_t*)((char*)d_ws + 16 * 32 * 64 * 8 * 2);  // next 512 KB

  pack_u_kernel<<<128, 256, 0, stream>>>(U, Upk);
  pack_w_kernel<<<128, 256, 0, stream>>>(W, Wpk);

  const size_t lds_bytes = (size_t)(BT * V_STRIDE + BT * T_STRIDE) * sizeof(bf16_t);  // 83456
  integrate_kernel<<<Bn / BT, 1024, lds_bytes, stream>>>(x, v, force, Upk, Wpk, steps, (float*)d_out);
}

// Round 3
// 802.803 us; speedup vs baseline: 2.5002x; 2.5002x over previous
//
#include <hip/hip_runtime.h>

typedef __bf16 bf16_t;
typedef __bf16 bf16x8 __attribute__((ext_vector_type(8)));
typedef float f32x4 __attribute__((ext_vector_type(4)));

#define MFMA_BF16(a, b, c) __builtin_amdgcn_mfma_f32_16x16x32_bf16((a), (b), (c), 0, 0, 0)

static constexpr int Bn = 4096;
static constexpr int Dn = 1024;
static constexpr int Rn = 256;
static constexpr int BT = 16;          // rows per block (one MFMA M-tile)
static constexpr int V_STRIDE = 1032;  // 2064 B rows: 16B-aligned, 2-way bank alias only (free)
static constexpr int T_STRIDE = 264;
static constexpr float DTv = 0.01f;
static constexpr float HDT = 0.005f;

// ---- Pack U [D=1024, R=256] fp32 -> bf16 B-operand fragment layout ----
// Upk[((ct*32 + kb)*64 + lane)*8 + j] = U[kb*32 + (lane>>4)*8 + j][ct*16 + (lane&15)]
__global__ void pack_u_kernel(const float* __restrict__ U, bf16_t* __restrict__ Upk) {
  int t = blockIdx.x * blockDim.x + threadIdx.x;  // 16*32*64 = 32768 threads
  int l = t & 63;
  int f = t >> 6;
  int kb = f & 31;
  int ct = f >> 5;
  int row0 = kb * 32 + (l >> 4) * 8;
  int col = ct * 16 + (l & 15);
  bf16x8 v;
#pragma unroll
  for (int j = 0; j < 8; ++j) v[j] = (bf16_t)U[(size_t)(row0 + j) * Rn + col];
  ((bf16x8*)Upk)[t] = v;
}

// ---- Pack W [R=256, D=1024] fp32 -> bf16 B-operand fragment layout ----
// Wpk[((ct*8 + kb)*64 + lane)*8 + j] = W[kb*32 + (lane>>4)*8 + j][ct*16 + (lane&15)]
__global__ void pack_w_kernel(const float* __restrict__ W, bf16_t* __restrict__ Wpk) {
  int t = blockIdx.x * blockDim.x + threadIdx.x;  // 64*8*64 = 32768 threads
  int l = t & 63;
  int f = t >> 6;
  int kb = f & 7;
  int ct = f >> 3;
  int row0 = kb * 32 + (l >> 4) * 8;
  int col = ct * 16 + (l & 15);
  bf16x8 v;
#pragma unroll
  for (int j = 0; j < 8; ++j) v[j] = (bf16_t)W[(size_t)(row0 + j) * Dn + col];
  ((bf16x8*)Wpk)[t] = v;
}

// ---- Fused integrator: 256 blocks x 1024 threads; block owns 16 rows for all steps ----
// Wave wv (0..15): phase 1 computes R-column-tile ct=wv of hv = v@U;
//                  phase 2 computes D-column-tiles 4wv..4wv+3 of gamma = T@W,
//                  which are exactly its own 64 state columns.
// Steady-state global traffic: U/W fragments only (L2-resident, 1 MB/XCD).
__global__ __launch_bounds__(1024)
void integrate_kernel(const float* __restrict__ x_in, const float* __restrict__ v_in,
                      const float* __restrict__ force,
                      const bf16_t* __restrict__ Upk, const bf16_t* __restrict__ Wpk,
                      const int* __restrict__ steps_p, float* __restrict__ out) {
  __shared__ __align__(16) bf16_t vbf[BT * V_STRIDE];  // v tile (x tile during phase 0)
  __shared__ __align__(16) bf16_t tbf[BT * T_STRIDE];  // T = tanh(hx)*hv^2 tile

  const int tid = (int)threadIdx.x;
  const int wv = tid >> 6;   // 0..15
  const int l = tid & 63;
  const int ln = l & 15;
  const int quad = l >> 4;
  const int nhalf = 2 * steps_p[0];
  const int row_base = (int)blockIdx.x * BT;

  float* out_x = out;
  float* out_v = out + (size_t)Bn * Dn;

  // State in registers, C/D layout. Element (i,r): row row_base+quad*4+r, col (wv*4+i)*16+ln
  float xs[4][4], vs[4][4], fs[4][4];
  f32x4 hx = {0.f, 0.f, 0.f, 0.f};  // (x@U) state for ct = wv

  // B-fragment stream bases
  const bf16x8* up = (const bf16x8*)Upk + (size_t)wv * 32 * 64 + l;       // ct = wv, 32 kbs
  const bf16x8* wp = (const bf16x8*)Wpk + (size_t)(wv * 4) * 8 * 64 + l;  // cts 4wv.., 8 kbs each

  bf16x8 ur[8];  // U prefetch ring (depth 8)
  auto preload_u = [&]() {
#pragma unroll
    for (int p = 0; p < 8; ++p) ur[p] = up[p * 64];
  };
  auto gemm_u = [&](f32x4& acc) {  // acc += tile(vbf)[16xD] @ U[:, ct-tile wv]
    const bf16_t* arow = vbf + ln * V_STRIDE + quad * 8;
#pragma unroll
    for (int kb = 0; kb < 32; ++kb) {
      const bf16x8 a = *(const bf16x8*)(arow + kb * 32);
      const bf16x8 b = ur[kb & 7];
      if (kb < 24) ur[kb & 7] = up[(kb + 8) * 64];
      acc = MFMA_BF16(a, b, acc);
    }
  };

  // ---- init: load x,v,force; x tile -> vbf for phase 0 ----
#pragma unroll
  for (int i = 0; i < 4; ++i) {
    const int col = (wv * 4 + i) * 16 + ln;
#pragma unroll
    for (int r = 0; r < 4; ++r) {
      const size_t g = (size_t)(row_base + quad * 4 + r) * Dn + col;
      xs[i][r] = x_in[g];
      vs[i][r] = v_in[g];
      fs[i][r] = force[g];
      vbf[(quad * 4 + r) * V_STRIDE + col] = (bf16_t)xs[i][r];
    }
  }
  preload_u();
  __syncthreads();

  // ---- phase 0: hx = x0 @ U ----
  gemm_u(hx);
  __syncthreads();  // everyone done reading x tile
#pragma unroll
  for (int i = 0; i < 4; ++i) {
    const int col = (wv * 4 + i) * 16 + ln;
#pragma unroll
    for (int r = 0; r < 4; ++r)
      vbf[(quad * 4 + r) * V_STRIDE + col] = (bf16_t)vs[i][r];
  }
  preload_u();
  __syncthreads();

  for (int h = 0; h < nhalf; ++h) {
    // ---- phase 1: hv(ct=wv) = v @ U ----
    f32x4 hv = {0.f, 0.f, 0.f, 0.f};
    gemm_u(hv);

    // issue W prefetch now; latency hidden behind T-epilogue + barrier
    bf16x8 wr[4][2];
#pragma unroll
    for (int i = 0; i < 4; ++i) {
      wr[i][0] = wp[i * 8 * 64];
      wr[i][1] = wp[i * 8 * 64 + 64];
    }

    const bool odd = (h & 1) != 0;
    if (odd) {  // x was updated with exactly this v: hx += dt * hv
#pragma unroll
      for (int r = 0; r < 4; ++r) hx[r] += DTv * hv[r];
    }
    // T = tanh(hx) * hv^2 -> tbf (bf16), ct = wv
#pragma unroll
    for (int r = 0; r < 4; ++r) {
      float a = fminf(fmaxf(hx[r], -15.f), 15.f);
      const float e = __expf(2.f * a);
      const float gate = (e - 1.f) / (e + 1.f);
      tbf[(quad * 4 + r) * T_STRIDE + wv * 16 + ln] = (bf16_t)(gate * hv[r] * hv[r]);
    }
    __syncthreads();

    // ---- phase 2: gamma(cts 4wv..4wv+3) = T @ W ----
    f32x4 acc[4];
#pragma unroll
    for (int i = 0; i < 4; ++i) acc[i] = (f32x4){0.f, 0.f, 0.f, 0.f};
    {
      const bf16_t* trow = tbf + ln * T_STRIDE + quad * 8;
#pragma unroll
      for (int kb = 0; kb < 8; ++kb) {
        const bf16x8 a = *(const bf16x8*)(trow + kb * 32);
#pragma unroll
        for (int i = 0; i < 4; ++i) {
          const bf16x8 b = wr[i][kb & 1];
          if (kb < 6) wr[i][kb & 1] = wp[i * 8 * 64 + (kb + 2) * 64];
          acc[i] = MFMA_BF16(a, b, acc[i]);
        }
      }
    }
    preload_u();  // for next half-step; hidden behind epilogue + barrier

    // ---- fused update: v += hdt*(force - gamma); even h: x += dt*v (all in regs) ----
#pragma unroll
    for (int i = 0; i < 4; ++i) {
      const int col = (wv * 4 + i) * 16 + ln;
#pragma unroll
      for (int r = 0; r < 4; ++r) {
        const float a = fs[i][r] - acc[i][r];
        vs[i][r] += HDT * a;
        if (!odd) xs[i][r] += DTv * vs[i][r];
        vbf[(quad * 4 + r) * V_STRIDE + col] = (bf16_t)vs[i][r];
      }
    }
    __syncthreads();
  }

  // ---- store x, v ----
#pragma unroll
  for (int i = 0; i < 4; ++i) {
    const int col = (wv * 4 + i) * 16 + ln;
#pragma unroll
    for (int r = 0; r < 4; ++r) {
      const size_t g = (size_t)(row_base + quad * 4 + r) * Dn + col;
      out_x[g] = xs[i][r];
      out_v[g] = vs[i][r];
    }
  }
}

extern "C" void kernel_launch(void* const* d_in, const int* in_sizes, int n_in,
                              void* d_out, int out_size, void* d_ws, size_t ws_size,
                              hipStream_t stream) {
  const float* x = (const float*)d_in[0];
  const float* v = (const float*)d_in[1];
  const float* force = (const float*)d_in[2];
  const float* U = (const float*)d_in[3];
  const float* W = (const float*)d_in[4];
  const int* steps = (const int*)d_in[5];

  bf16_t* Upk = (bf16_t*)d_ws;                                  // 512 KB
  bf16_t* Wpk = (bf16_t*)((char*)d_ws + 16 * 32 * 64 * 8 * 2);  // next 512 KB

  pack_u_kernel<<<128, 256, 0, stream>>>(U, Upk);
  pack_w_kernel<<<128, 256, 0, stream>>>(W, Wpk);

  integrate_kernel<<<Bn / BT, 1024, 0, stream>>>(x, v, force, Upk, Wpk, steps, (float*)d_out);
}

// Round 4
// 734.139 us; speedup vs baseline: 2.7340x; 1.0935x over previous
//
#include <hip/hip_runtime.h>

typedef __bf16 bf16_t;
typedef __bf16 bf16x2 __attribute__((ext_vector_type(2)));
typedef __bf16 bf16x8 __attribute__((ext_vector_type(8)));
typedef float f32x4 __attribute__((ext_vector_type(4)));

#define MFMA_BF16(a, b, c) __builtin_amdgcn_mfma_f32_16x16x32_bf16((a), (b), (c), 0, 0, 0)

static constexpr int Bn = 4096;
static constexpr int Dn = 1024;
static constexpr int Rn = 256;
static constexpr int BT = 16;          // rows per block (one MFMA M-tile)
static constexpr int V_STRIDE = 1032;  // 2064 B rows, 16B-aligned
static constexpr int T_STRIDE = 264;
static constexpr float DTv = 0.01f;
static constexpr float HDT = 0.005f;

// ---- Pack U [D=1024, R=256] fp32 -> bf16 B-operand fragment layout ----
// Upk[((ct*32 + kb)*64 + lane)*8 + j] = U[kb*32 + (lane>>4)*8 + j][ct*16 + (lane&15)]
__global__ void pack_u_kernel(const float* __restrict__ U, bf16_t* __restrict__ Upk) {
  int t = blockIdx.x * blockDim.x + threadIdx.x;  // 16*32*64 = 32768 threads
  int l = t & 63;
  int f = t >> 6;
  int kb = f & 31;
  int ct = f >> 5;
  int row0 = kb * 32 + (l >> 4) * 8;
  int col = ct * 16 + (l & 15);
  bf16x8 v;
#pragma unroll
  for (int j = 0; j < 8; ++j) v[j] = (bf16_t)U[(size_t)(row0 + j) * Rn + col];
  ((bf16x8*)Upk)[t] = v;
}

// ---- Pack W [R=256, D=1024] fp32 -> bf16 B-operand fragment layout ----
// Wpk[((ct*8 + kb)*64 + lane)*8 + j] = W[kb*32 + (lane>>4)*8 + j][ct*16 + (lane&15)]
__global__ void pack_w_kernel(const float* __restrict__ W, bf16_t* __restrict__ Wpk) {
  int t = blockIdx.x * blockDim.x + threadIdx.x;  // 64*8*64 = 32768 threads
  int l = t & 63;
  int f = t >> 6;
  int kb = f & 7;
  int ct = f >> 3;
  int row0 = kb * 32 + (l >> 4) * 8;
  int col = ct * 16 + (l & 15);
  bf16x8 v;
#pragma unroll
  for (int j = 0; j < 8; ++j) v[j] = (bf16_t)W[(size_t)(row0 + j) * Dn + col];
  ((bf16x8*)Wpk)[t] = v;
}

// ---- Fused integrator: 256 blocks x 1024 threads; block owns 16 rows for all steps ----
// Wave wv (0..15): phase 1 computes R-ct wv of hv = v@U; phase 2 computes D-cts
// 4wv..4wv+3 of gamma = T@W == its own 64 state columns. Steady-state global
// traffic: U/W fragments only (1 MB, L2-resident per XCD).
// amdgpu_waves_per_eu(4,4): we run exactly 1 block/CU = 4 waves/EU, so cap the
// occupancy heuristic there -> 128-VGPR budget -> no spills (R2/R3 failure mode).
__global__ __launch_bounds__(1024)
__attribute__((amdgpu_waves_per_eu(4, 4)))
void integrate_kernel(const float* __restrict__ x_in, const float* __restrict__ v_in,
                      const float* __restrict__ force,
                      const bf16_t* __restrict__ Upk, const bf16_t* __restrict__ Wpk,
                      const int* __restrict__ steps_p, float* __restrict__ out) {
  __shared__ __align__(16) bf16_t vbf[BT * V_STRIDE];  // v tile (x tile during phase 0)
  __shared__ __align__(16) bf16_t tbf[BT * T_STRIDE];  // T = tanh(hx)*hv^2 tile

  const int tid = (int)threadIdx.x;
  const int wv = tid >> 6;   // 0..15
  const int l = tid & 63;
  const int ln = l & 15;
  const int quad = l >> 4;
  const int nhalf = 2 * steps_p[0];
  const int row_base = (int)blockIdx.x * BT;

  float* out_x = out;
  float* out_v = out + (size_t)Bn * Dn;

  // Register state, C/D layout. Element (i,r): row row_base+quad*4+r, col (wv*4+i)*16+ln
  float xs[4][4], vs[4][4];
  bf16x2 fs2[4][2];                 // force, packed bf16 (8 VGPRs)
  f32x4 hx = {0.f, 0.f, 0.f, 0.f};  // cached (x@U) for ct = wv

  // B-fragment stream bases
  const bf16x8* up = (const bf16x8*)Upk + (size_t)wv * 32 * 64 + l;       // ct = wv
  const bf16x8* wp = (const bf16x8*)Wpk + (size_t)(wv * 4) * 8 * 64 + l;  // cts 4wv..4wv+3

  // acc += tile(vbf)[16xD] @ U[:, ct-tile wv]; depth-4 register ring
  auto gemm_u = [&](f32x4& acc) {
    const bf16_t* arow = vbf + ln * V_STRIDE + quad * 8;
    bf16x8 ur[4];
#pragma unroll
    for (int p = 0; p < 4; ++p) ur[p] = up[p * 64];
#pragma unroll
    for (int kb = 0; kb < 32; ++kb) {
      const bf16x8 a = *(const bf16x8*)(arow + kb * 32);
      const bf16x8 b = ur[kb & 3];
      if (kb < 28) ur[kb & 3] = up[(kb + 4) * 64];
      acc = MFMA_BF16(a, b, acc);
    }
  };

  // ---- init: load x,v,force; x tile -> vbf for phase 0 ----
#pragma unroll
  for (int i = 0; i < 4; ++i) {
    const int col = (wv * 4 + i) * 16 + ln;
#pragma unroll
    for (int r = 0; r < 4; ++r) {
      const size_t g = (size_t)(row_base + quad * 4 + r) * Dn + col;
      xs[i][r] = x_in[g];
      vs[i][r] = v_in[g];
      fs2[i][r >> 1][r & 1] = (bf16_t)force[g];
      vbf[(quad * 4 + r) * V_STRIDE + col] = (bf16_t)xs[i][r];
    }
  }
  __syncthreads();

  // ---- phase 0: hx = x0 @ U ----
  gemm_u(hx);
  __syncthreads();  // everyone done reading x tile
#pragma unroll
  for (int i = 0; i < 4; ++i) {
    const int col = (wv * 4 + i) * 16 + ln;
#pragma unroll
    for (int r = 0; r < 4; ++r)
      vbf[(quad * 4 + r) * V_STRIDE + col] = (bf16_t)vs[i][r];
  }
  __syncthreads();

  for (int h = 0; h < nhalf; ++h) {
    // ---- phase 1: hv(ct=wv) = v @ U ----
    f32x4 hv = {0.f, 0.f, 0.f, 0.f};
    gemm_u(hv);

    const bool odd = (h & 1) != 0;
    if (odd) {  // x was updated with exactly this v: hx += dt * hv
#pragma unroll
      for (int r = 0; r < 4; ++r) hx[r] += DTv * hv[r];
    }
    // T = tanh(hx) * hv^2 -> tbf (bf16), ct = wv
#pragma unroll
    for (int r = 0; r < 4; ++r) {
      float a = fminf(fmaxf(hx[r], -15.f), 15.f);
      const float e = __expf(2.f * a);
      const float gate = (e - 1.f) / (e + 1.f);
      tbf[(quad * 4 + r) * T_STRIDE + wv * 16 + ln] = (bf16_t)(gate * hv[r] * hv[r]);
    }
    __syncthreads();

    // ---- phase 2: gamma(cts 4wv..4wv+3) = T @ W; depth-1 per-stream prefetch ----
    f32x4 acc[4];
#pragma unroll
    for (int i = 0; i < 4; ++i) acc[i] = (f32x4){0.f, 0.f, 0.f, 0.f};
    {
      const bf16_t* trow = tbf + ln * T_STRIDE + quad * 8;
      bf16x8 wr[4];
#pragma unroll
      for (int i = 0; i < 4; ++i) wr[i] = wp[i * 8 * 64];
#pragma unroll
      for (int kb = 0; kb < 8; ++kb) {
        const bf16x8 a = *(const bf16x8*)(trow + kb * 32);
#pragma unroll
        for (int i = 0; i < 4; ++i) {
          const bf16x8 b = wr[i];
          if (kb < 7) wr[i] = wp[i * 8 * 64 + (kb + 1) * 64];
          acc[i] = MFMA_BF16(a, b, acc[i]);
        }
      }
    }

    // ---- fused update: v += hdt*(force - gamma); even h: x += dt*v (regs only) ----
#pragma unroll
    for (int i = 0; i < 4; ++i) {
      const int col = (wv * 4 + i) * 16 + ln;
#pragma unroll
      for (int r = 0; r < 4; ++r) {
        const float fval = (float)fs2[i][r >> 1][r & 1];
        vs[i][r] += HDT * (fval - acc[i][r]);
        if (!odd) xs[i][r] += DTv * vs[i][r];
        vbf[(quad * 4 + r) * V_STRIDE + col] = (bf16_t)vs[i][r];
      }
    }
    __syncthreads();
  }

  // ---- store x, v ----
#pragma unroll
  for (int i = 0; i < 4; ++i) {
    const int col = (wv * 4 + i) * 16 + ln;
#pragma unroll
    for (int r = 0; r < 4; ++r) {
      const size_t g = (size_t)(row_base + quad * 4 + r) * Dn + col;
      out_x[g] = xs[i][r];
      out_v[g] = vs[i][r];
    }
  }
}

extern "C" void kernel_launch(void* const* d_in, const int* in_sizes, int n_in,
                              void* d_out, int out_size, void* d_ws, size_t ws_size,
                              hipStream_t stream) {
  const float* x = (const float*)d_in[0];
  const float* v = (const float*)d_in[1];
  const float* force = (const float*)d_in[2];
  const float* U = (const float*)d_in[3];
  const float* W = (const float*)d_in[4];
  const int* steps = (const int*)d_in[5];

  bf16_t* Upk = (bf16_t*)d_ws;                                  // 512 KB
  bf16_t* Wpk = (bf16_t*)((char*)d_ws + 16 * 32 * 64 * 8 * 2);  // next 512 KB

  pack_u_kernel<<<128, 256, 0, stream>>>(U, Upk);
  pack_w_kernel<<<128, 256, 0, stream>>>(W, Wpk);

  integrate_kernel<<<Bn / BT, 1024, 0, stream>>>(x, v, force, Upk, Wpk, steps, (float*)d_out);
}